// Round 1
// 271.944 us; speedup vs baseline: 1.0031x; 1.0031x over previous
//
#include <hip/hip_runtime.h>
#include <hip/hip_bf16.h>

#define NTOK 49
#define CDIM 128
#define SCALE 0.17677669529663687f

// packed table sizes (elements)
#define MASKT_ELEMS (64*64*16*4)      // 262144 f32  [w][m][ln][ct] = mask + pad (-1e30 rows m>=49)
#define RPBT_ELEMS  (4*64*16*4)       // 16384 f32   [h][m][ln][ct]
#define PWQK_ELEMS  (4*4*4*4*16*8)    // 32768 bf16  [h][rt][ks][quad][ln][j]  (A-frags of Wq/Wk^T)
#define PV_ELEMS    (8*4*4*16*8)      // 16384 bf16  [c2][ks][quad][ln][j]     (B-frags of Wv)
#define PWP_ELEMS   (8*4*4*16*8)      // 16384 bf16  [rt][ks][quad][ln][j]     (A-frags of Wproj^T)

// LDS layout (units: shorts), per head region HSZ:
//   q[n 0..63][d stride QS=36] @0 ; k @KOFFS ; P[n][m stride PS=68] aliases q+k
//   v^T[d 0..31][m stride VS=68] @VOFFS ; O-slice[n<56][c-in-head stride OS=36] aliases v
// All row strides are mult-of-4 shorts (8B-aligned b64 ops) with stride/2 ≡ 2 mod 4
// -> 16-lane access spreads over 16 distinct bank(-pair)s: 2-way aliasing = free (m136).
#define QS 36
#define PS 68
#define VS 68
#define OS 36
#define KOFFS (64*QS)          // 2304
#define VOFFS (2*KOFFS)        // 4608
#define HSZ   (VOFFS + 32*VS)  // 6784
// 27136 shorts = 54272 B = 106*512 exactly -> allocator does NOT round up
// -> 3*54272 = 162816 <= 163840 -> 3 blocks/CU (the old +128-short tail pad
// pushed the rounded allocation to 54784 B, silently dropping to 2 blocks/CU).
// Stage-D ld8 of O rows n>=60 in head 3 reads past this array; those rows are
// never written (n<56 guard), are non-faulting LDS reads, and feed only output
// columns n>=49 which the n<NTOK store guard discards — provably dead values.
#define LDS_SH (4*HSZ)         // 27136 shorts = 54272 B

typedef __attribute__((ext_vector_type(8))) __bf16 bf16x8;
typedef __attribute__((ext_vector_type(4))) float f32x4;

__device__ __forceinline__ unsigned short f2bf(float f) {
  unsigned int u = __float_as_uint(f);
  u += 0x7fffu + ((u >> 16) & 1u);   // RTNE
  return (unsigned short)(u >> 16);
}

__device__ __forceinline__ unsigned int pk2(float a, float b) {
  union { __hip_bfloat162 h2; unsigned int u; } r;
  r.h2 = __float22bfloat162_rn(make_float2(a, b));
  return r.u;
}
__device__ __forceinline__ unsigned long long pk4(float a, float b, float c, float d) {
  return (unsigned long long)pk2(a, b) | ((unsigned long long)pk2(c, d) << 32);
}
__device__ __forceinline__ bf16x8 pack8(float4 a, float4 b) {
  union { bf16x8 v; unsigned int u[4]; } r;
  r.u[0] = pk2(a.x, a.y); r.u[1] = pk2(a.z, a.w);
  r.u[2] = pk2(b.x, b.y); r.u[3] = pk2(b.z, b.w);
  return r.v;
}
// two ds_read_b64 (rows are 8B- but not 16B-aligned)
__device__ __forceinline__ bf16x8 ld8(const unsigned short* p) {
  union { bf16x8 v; unsigned long long q[2]; } r;
  r.q[0] = *(const unsigned long long*)(p);
  r.q[1] = *(const unsigned long long*)(p + 4);
  return r.v;
}

// ---- prep: swizzled mask/rpb tables + weight fragments ----
__global__ void prep_kernel(const float* __restrict__ mask,
                            const float* __restrict__ qkv_w,
                            const float* __restrict__ proj_w,
                            const float* __restrict__ bias_table,
                            const int* __restrict__ rel_index,
                            float* __restrict__ mask_t,
                            float* __restrict__ rpb_t,
                            unsigned short* __restrict__ pwqk,
                            unsigned short* __restrict__ pv,
                            unsigned short* __restrict__ pwp) {
  int i = blockIdx.x * 256 + threadIdx.x;
  if (i < MASKT_ELEMS) {
    int ct = i & 3, ln = (i >> 2) & 15, m = (i >> 6) & 63, w = i >> 12;
    int n = ct * 16 + ln;
    float v;
    if (m < NTOK) v = (n < NTOK) ? mask[(w * NTOK + n) * NTOK + m] : 0.0f;
    else          v = -1e30f;     // rows m>=49: exp -> 0
    mask_t[i] = v;
    return;
  }
  i -= MASKT_ELEMS;
  if (i < RPBT_ELEMS) {
    int ct = i & 3, ln = (i >> 2) & 15, m = (i >> 6) & 63, h = i >> 12;
    int n = ct * 16 + ln;
    rpb_t[i] = (m < NTOK && n < NTOK) ? bias_table[rel_index[n * NTOK + m] * 4 + h] : 0.0f;
    return;
  }
  i -= RPBT_ELEMS;
  if (i < PWQK_ELEMS) {
    int j = i & 7, ln = (i >> 3) & 15, quad = (i >> 7) & 3, ks = (i >> 9) & 3,
        rt = (i >> 11) & 3, h = (i >> 13) & 3;
    int kk  = ks * 32 + quad * 8 + j;
    int col = (rt < 2) ? (h * 32 + rt * 16 + ln) : (128 + h * 32 + (rt - 2) * 16 + ln);
    pwqk[i] = f2bf(qkv_w[kk * 384 + col]);
    return;
  }
  i -= PWQK_ELEMS;
  if (i < PV_ELEMS) {
    int j = i & 7, ln = (i >> 3) & 15, quad = (i >> 7) & 3, ks = (i >> 9) & 3, c2 = (i >> 11) & 7;
    pv[i] = f2bf(qkv_w[(ks * 32 + quad * 8 + j) * 384 + 256 + c2 * 16 + ln]);
    return;
  }
  i -= PV_ELEMS;
  if (i < PWP_ELEMS) {
    int j = i & 7, ln = (i >> 3) & 15, quad = (i >> 7) & 3, ks = (i >> 9) & 3, rt = (i >> 11) & 7;
    pwp[i] = f2bf(proj_w[(ks * 32 + quad * 8 + j) * 128 + rt * 16 + ln]);
  }
}

// ---- fused window attention: 1 block = 1 window, wave h owns head h; ONE barrier total ----
__global__ __launch_bounds__(256, 3) void win_attn_kernel(
    const float* __restrict__ x,
    const float* __restrict__ qkv_b,
    const float* __restrict__ proj_b,
    const float* __restrict__ mask_t,
    const float* __restrict__ rpb_t,
    const unsigned short* __restrict__ pwqk,
    const unsigned short* __restrict__ pv,
    const unsigned short* __restrict__ pwp,
    float* __restrict__ out)
{
  __shared__ alignas(16) unsigned short lds[LDS_SH];

  const int b    = blockIdx.x;
  const int tid  = threadIdx.x;
  const int h    = tid >> 6;
  const int lane = tid & 63;
  const int ln   = lane & 15;
  const int quad = lane >> 4;

  unsigned short* hb = lds + h * HSZ;

  // ---- x fragments from global: serve as A (rows=tokens) for v-GEMM and B (cols=tokens) for q/k ----
  bf16x8 afr[4][4];
  {
    const float* xb = x + (size_t)b * (NTOK * CDIM);
    #pragma unroll
    for (int rt = 0; rt < 4; rt++) {
      const int row = rt * 16 + ln;
      #pragma unroll
      for (int ks = 0; ks < 4; ks++) {
        if (row < NTOK) {
          const float* p = xb + row * CDIM + ks * 32 + quad * 8;
          afr[rt][ks] = pack8(*(const float4*)p, *(const float4*)(p + 4));
        } else {
          union { bf16x8 v; unsigned int u[4]; } z;
          z.u[0] = z.u[1] = z.u[2] = z.u[3] = 0u;
          afr[rt][ks] = z.v;   // pad tokens -> 0; downstream q/k/v pad entries = bias (finite)
        }
      }
    }
  }

  // ---------------- stage A-v: v = x @ Wv (normal orient; C rows=tokens) ----------------
  #pragma unroll
  for (int ci = 0; ci < 2; ci++) {
    bf16x8 bvf[4];
    #pragma unroll
    for (int ks = 0; ks < 4; ks++)
      bvf[ks] = *(const bf16x8*)&pv[((((h*2 + ci)*4 + ks)*4 + quad)*16 + ln)*8];
    const float bvb = qkv_b[256 + (h*2 + ci)*16 + ln];
    f32x4 acc[4];
    #pragma unroll
    for (int rt = 0; rt < 4; rt++) { f32x4 bi = {bvb, bvb, bvb, bvb}; acc[rt] = bi; }
    #pragma unroll
    for (int ks = 0; ks < 4; ks++)
      #pragma unroll
      for (int rt = 0; rt < 4; rt++)
        acc[rt] = __builtin_amdgcn_mfma_f32_16x16x32_bf16(afr[rt][ks], bvf[ks], acc[rt], 0, 0, 0);
    // C: row=token m (quad*4+r), col=d (ln)  ->  v^T[d][m], m r-consecutive -> b64
    #pragma unroll
    for (int rt = 0; rt < 4; rt++)
      *(unsigned long long*)&hb[VOFFS + (ci*16 + ln)*VS + rt*16 + quad*4] =
          pk4(acc[rt][0], acc[rt][1], acc[rt][2], acc[rt][3]);
  }

  // ---------------- stage A-qk: qkv^T = W^T @ x^T (C rows=features) ----------------
  #pragma unroll
  for (int rt = 0; rt < 4; rt++) {
    bf16x8 awf[4];
    #pragma unroll
    for (int ks = 0; ks < 4; ks++)
      awf[ks] = *(const bf16x8*)&pwqk[((((h*4 + rt)*4 + ks)*4 + quad)*16 + ln)*8];
    const int fb = (rt < 2) ? (h*32 + rt*16 + quad*4) : (128 + h*32 + (rt - 2)*16 + quad*4);
    const float4 qb4 = *(const float4*)&qkv_b[fb];
    f32x4 acc2[4];
    #pragma unroll
    for (int ct = 0; ct < 4; ct++) { f32x4 bi = {qb4.x, qb4.y, qb4.z, qb4.w}; acc2[ct] = bi; }
    #pragma unroll
    for (int ks = 0; ks < 4; ks++)
      #pragma unroll
      for (int ct = 0; ct < 4; ct++)
        acc2[ct] = __builtin_amdgcn_mfma_f32_16x16x32_bf16(awf[ks], afr[ct][ks], acc2[ct], 0, 0, 0);
    // C: row=feature (quad*4+r), col=token n (ln) -> q[n][d] / k[m][d], d r-consecutive -> b64
    const int base = (rt < 2) ? 0 : KOFFS;
    const int d0   = (rt < 2) ? (rt*16 + quad*4) : ((rt - 2)*16 + quad*4);
    const float sc = (rt < 2) ? SCALE : 1.0f;   // fold softmax scale into q
    #pragma unroll
    for (int ct = 0; ct < 4; ct++)
      *(unsigned long long*)&hb[base + (ct*16 + ln)*QS + d0] =
          pk4(acc2[ct][0]*sc, acc2[ct][1]*sc, acc2[ct][2]*sc, acc2[ct][3]*sc);
  }

  // ---------------- stage B: S^T = k · q^T, acc-initialized with mask+rpb ----------------
  f32x4 sacc[4][4];   // [rt: m-tile][ct: n-tile]
  {
    const float* mw = mask_t + (size_t)(b & 63) * (64*64);
    const float* rw = rpb_t  + (size_t)h * (64*64);
    #pragma unroll
    for (int rt = 0; rt < 4; rt++)
      #pragma unroll
      for (int r = 0; r < 4; r++) {
        const int m = rt*16 + quad*4 + r;
        const float4 fm = *(const float4*)(mw + (m*16 + ln)*4);
        const float4 fr = *(const float4*)(rw + (m*16 + ln)*4);
        sacc[rt][0][r] = fm.x + fr.x;
        sacc[rt][1][r] = fm.y + fr.y;
        sacc[rt][2][r] = fm.z + fr.z;
        sacc[rt][3][r] = fm.w + fr.w;
      }
    bf16x8 ka[4], qb2[4];
    #pragma unroll
    for (int rt = 0; rt < 4; rt++) ka[rt]  = ld8(&hb[KOFFS + (rt*16 + ln)*QS + quad*8]);
    #pragma unroll
    for (int ct = 0; ct < 4; ct++) qb2[ct] = ld8(&hb[(ct*16 + ln)*QS + quad*8]);
    #pragma unroll
    for (int rt = 0; rt < 4; rt++)
      #pragma unroll
      for (int ct = 0; ct < 4; ct++)
        sacc[rt][ct] = __builtin_amdgcn_mfma_f32_16x16x32_bf16(ka[rt], qb2[ct], sacc[rt][ct], 0, 0, 0);
  }

  // ---------------- softmax over m (rows): lane-partial + 2 shuffles ----------------
  float inv[4];
  #pragma unroll
  for (int ct = 0; ct < 4; ct++) {
    float s = 0.0f;
    #pragma unroll
    for (int rt = 0; rt < 4; rt++)
      #pragma unroll
      for (int r = 0; r < 4; r++) {
        const float e = __expf(sacc[rt][ct][r]);   // m>=49 rows: -1e30 -> 0
        sacc[rt][ct][r] = e;
        s += e;
      }
    s += __shfl_xor(s, 16, 64);
    s += __shfl_xor(s, 32, 64);
    inv[ct] = 1.0f / s;
  }
  // P[n][m] (m r-consecutive -> b64); aliases own q/k region (per-wave DS is in-order)
  #pragma unroll
  for (int rt = 0; rt < 4; rt++)
    #pragma unroll
    for (int ct = 0; ct < 4; ct++)
      *(unsigned long long*)&hb[(ct*16 + ln)*PS + rt*16 + quad*4] =
          pk4(sacc[rt][ct][0]*inv[ct], sacc[rt][ct][1]*inv[ct],
              sacc[rt][ct][2]*inv[ct], sacc[rt][ct][3]*inv[ct]);

  // ---------------- stage C: O^T = v^T · P^T (C rows=d, cols=n) ----------------
  {
    bf16x8 va[2][2], pb[4][2];
    #pragma unroll
    for (int rt = 0; rt < 2; rt++)
      #pragma unroll
      for (int ks = 0; ks < 2; ks++)
        va[rt][ks] = ld8(&hb[VOFFS + (rt*16 + ln)*VS + ks*32 + quad*8]);
    #pragma unroll
    for (int ct = 0; ct < 4; ct++)
      #pragma unroll
      for (int ks = 0; ks < 2; ks++)
        pb[ct][ks] = ld8(&hb[(ct*16 + ln)*PS + ks*32 + quad*8]);
    f32x4 oacc[2][4];
    #pragma unroll
    for (int rt = 0; rt < 2; rt++)
      #pragma unroll
      for (int ct = 0; ct < 4; ct++) { f32x4 z = {0.f, 0.f, 0.f, 0.f}; oacc[rt][ct] = z; }
    #pragma unroll
    for (int ks = 0; ks < 2; ks++)
      #pragma unroll
      for (int rt = 0; rt < 2; rt++)
        #pragma unroll
        for (int ct = 0; ct < 4; ct++)
          oacc[rt][ct] = __builtin_amdgcn_mfma_f32_16x16x32_bf16(va[rt][ks], pb[ct][ks], oacc[rt][ct], 0, 0, 0);
    // O[n][c-in-head] (c r-consecutive -> b64) into own head's O slice (aliases own v; no barrier needed)
    #pragma unroll
    for (int rt = 0; rt < 2; rt++)
      #pragma unroll
      for (int ct = 0; ct < 4; ct++) {
        const int n = ct*16 + ln;
        if (n < 56)   // rows 56..63 would spill into the next head's region
          *(unsigned long long*)&hb[VOFFS + n*OS + rt*16 + quad*4] =
              pk4(oacc[rt][ct][0], oacc[rt][ct][1], oacc[rt][ct][2], oacc[rt][ct][3]);
      }
  }

  __syncthreads();   // the ONLY barrier: O slices complete before cross-head reads

  // ---------------- stage D: out^T = Wproj^T · O^T; float4 global stores ----------------
  {
    bf16x8 ob[4][4];  // [ct: n-tile][ks: c-in 32-chunk] ; chunk ks lives in head-ks's region
    #pragma unroll
    for (int ct = 0; ct < 4; ct++)
      #pragma unroll
      for (int ks = 0; ks < 4; ks++)
        ob[ct][ks] = ld8(&lds[ks*HSZ + VOFFS + (ct*16 + ln)*OS + quad*8]);
    float* obp = out + (size_t)b * (NTOK * CDIM);
    #pragma unroll
    for (int rt = 0; rt < 2; rt++) {
      bf16x8 wpa[4];
      #pragma unroll
      for (int ks = 0; ks < 4; ks++)
        wpa[ks] = *(const bf16x8*)&pwp[((((h*2 + rt)*4 + ks)*4 + quad)*16 + ln)*8];
      const int c0 = (h*2 + rt)*16 + quad*4;
      const float4 pb4 = *(const float4*)&proj_b[c0];
      f32x4 pacc[4];
      #pragma unroll
      for (int ct = 0; ct < 4; ct++) { f32x4 bi = {pb4.x, pb4.y, pb4.z, pb4.w}; pacc[ct] = bi; }
      #pragma unroll
      for (int ks = 0; ks < 4; ks++)
        #pragma unroll
        for (int ct = 0; ct < 4; ct++)
          pacc[ct] = __builtin_amdgcn_mfma_f32_16x16x32_bf16(wpa[ks], ob[ct][ks], pacc[ct], 0, 0, 0);
      #pragma unroll
      for (int ct = 0; ct < 4; ct++) {
        const int n = ct*16 + ln;
        if (n < NTOK) {
          float4 v4;
          v4.x = pacc[ct][0]; v4.y = pacc[ct][1]; v4.z = pacc[ct][2]; v4.w = pacc[ct][3];
          *(float4*)(obp + n*CDIM + c0) = v4;
        }
      }
    }
  }
}

extern "C" void kernel_launch(void* const* d_in, const int* in_sizes, int n_in,
                              void* d_out, int out_size, void* d_ws, size_t ws_size,
                              hipStream_t stream) {
  const float* x          = (const float*)d_in[0];
  const float* mask       = (const float*)d_in[1];
  const float* qkv_w      = (const float*)d_in[2];
  const float* qkv_b      = (const float*)d_in[3];
  const float* proj_w     = (const float*)d_in[4];
  const float* proj_b     = (const float*)d_in[5];
  const float* bias_table = (const float*)d_in[6];
  const int*   rel_index  = (const int*)d_in[7];
  float* out = (float*)d_out;

  char* ws = (char*)d_ws;
  float* mask_t         = (float*)ws;
  float* rpb_t          = (float*)(ws + (size_t)MASKT_ELEMS*4);
  unsigned short* pwqk  = (unsigned short*)(ws + (size_t)(MASKT_ELEMS + RPBT_ELEMS)*4);
  unsigned short* pv    = (unsigned short*)(ws + (size_t)(MASKT_ELEMS + RPBT_ELEMS)*4 + (size_t)PWQK_ELEMS*2);
  unsigned short* pwp   = (unsigned short*)(ws + (size_t)(MASKT_ELEMS + RPBT_ELEMS)*4 + (size_t)(PWQK_ELEMS + PV_ELEMS)*2);

  const int total = MASKT_ELEMS + RPBT_ELEMS + PWQK_ELEMS + PV_ELEMS + PWP_ELEMS;
  prep_kernel<<<(total + 255)/256, 256, 0, stream>>>(
      mask, qkv_w, proj_w, bias_table, rel_index, mask_t, rpb_t, pwqk, pv, pwp);
  win_attn_kernel<<<4096, 256, 0, stream>>>(
      x, qkv_b, proj_b, mask_t, rpb_t, pwqk, pv, pwp, out);
}